// Round 15
// baseline (31.674 us; speedup 1.0000x reference)
//
#include <hip/hip_runtime.h>

constexpr int KWIN = 100;
constexpr int HK   = 50;
constexpr int TSUB = 64;           // outputs per span
constexpr int CF   = 16;           // frames per chunk
constexpr int CFL  = 2 * CF * 128; // floats per chunk (2 b's) = 4096 (16 KB)

typedef float f32x4 __attribute__((ext_vector_type(4)));

__device__ __forceinline__ int ridx(int t) {
    constexpr int T = 16384;
    t = (t < 0) ? -t : t;
    return (t >= T) ? (2 * T - 2 - t) : t;
}

__global__ __launch_bounds__(256, 2) void man_kernel(
    const float* __restrict__ x, float* __restrict__ out)
{
    constexpr int T = 16384, D = 128;
    __shared__ float lds[3 * CFL];            // 48 KB -> 3 blocks/CU

    const int i  = blockIdx.x;                // 0..1023
    const int bb = (i & 7) * 128 + (i >> 3);  // XCD chunked swizzle (1024%8==0)
    const int bp = bb >> 8;                   // bpair 0..3
    const int sp = bb & 255;                  // span 0..255
    const int t0 = sp * TSUB;
    const int tid  = threadIdx.x;
    const int bsel = tid >> 7;                // which b of the pair
    const int d    = tid & 127;               // column
    const int b    = bp * 2 + bsel;

    const float invK = 1.0f / 100.0f, invKm1 = 1.0f / 99.0f, fK = 100.0f;

    float ring[KWIN];                         // window in registers, static idx
    float sx = 0.f, sq = 0.f;
    float* ob = out + (size_t)b * T * D + d;

    if (sp == 0 || sp == 255) {
        // ---------- boundary spans: private reflect path, NO barriers ----------
        const float* xb = x + (size_t)b * T * D + d;
        #pragma unroll
        for (int s = 0; s < KWIN; ++s) {
            float v = xb[(size_t)ridx(t0 - HK + s) * D];
            ring[s] = v; sx += v; sq = fmaf(v, v, sq);
        }
        #pragma unroll
        for (int k = 0; k < TSUB; ++k) {
            float inv = xb[(size_t)ridx(t0 + k + HK) * D];
            float o  = ring[k];
            float cc = (k < HK) ? ring[k + HK] : ring[k - HK];
            float m  = sx * invK;
            float va = fmaxf((sq - fK * m * m) * invKm1, 1e-24f);
            float rs = __builtin_amdgcn_rsqf(va);
            __builtin_nontemporal_store((cc - m) * rs, &ob[(size_t)(t0 + k) * D]);
            sx += inv - o; sq += inv * inv - o * o;
            ring[k] = inv;
        }
        return;
    }

    // ---------- interior: cooperative LDS staging ----------
    // Chunk c stages frames [t0-50+16c, t0-50+16c+16) for BOTH b's of the pair:
    // 16 KB contiguous-per-b, loaded once per block, consumed via ds_read.
    const float* gb0 = x + (size_t)(bp * 2 + 0) * T * D;
    const float* gb1 = x + (size_t)(bp * 2 + 1) * T * D;
    const float* lrd = &lds[bsel * (CF * 128)];   // + slot*CFL + j*128 + d

    f32x4 rA[4], rB[4];

#define SLOAD(c, R) {                                                         \
    const int F0_ = t0 - HK + CF * (c);                                       \
    _Pragma("unroll")                                                         \
    for (int r = 0; r < 4; ++r) {                                             \
        const float* g_ = (r < 2)                                             \
            ? (gb0 + (size_t)F0_ * D + tid * 4 + r * 1024)                    \
            : (gb1 + (size_t)F0_ * D + tid * 4 + (r - 2) * 1024);             \
        R[r] = *(const f32x4*)g_; } }

#define SWRITE(c, R) {                                                        \
    float* lb_ = &lds[((c) % 3) * CFL];                                       \
    _Pragma("unroll")                                                         \
    for (int r = 0; r < 4; ++r)                                               \
        *(f32x4*)(lb_ + tid * 4 + r * 1024) = R[r]; }

    // lgkm drain + barrier in ONE asm: no vmcnt drain (prefetch loads stay in
    // flight across the barrier), and "memory" fences LDS ops at IR level.
#define BARRIER() {                                                           \
    asm volatile("s_waitcnt lgkmcnt(0)\n\ts_barrier" ::: "memory");           \
    __builtin_amdgcn_sched_barrier(0); }

#define CPRIME(c, JHI) {                                                      \
    const float* lb_ = lrd + ((c) % 3) * CFL;                                 \
    _Pragma("unroll")                                                         \
    for (int j = 0; j < (JHI); ++j) {                                         \
        float v = lb_[j * 128 + d];                                           \
        ring[16 * (c) + j] = v;                                               \
        sx += v; sq = fmaf(v, v, sq); } }

#define CMAIN(c, JLO, JHI) {                                                  \
    const float* lb_ = lrd + ((c) % 3) * CFL;                                 \
    _Pragma("unroll")                                                         \
    for (int j = (JLO); j < (JHI); ++j) {                                     \
        const int k = 16 * (c) + j - 100;                                     \
        float inv = lb_[j * 128 + d];                                         \
        float o  = ring[k];                                                   \
        float cc = (k < HK) ? ring[k + HK] : ring[k - HK];                    \
        float m  = sx * invK;                                                 \
        float va = fmaxf((sq - fK * m * m) * invKm1, 1e-24f);                 \
        float rs = __builtin_amdgcn_rsqf(va);                                 \
        __builtin_nontemporal_store((cc - m) * rs,                            \
                                    &ob[(size_t)(t0 + k) * D]);               \
        sx += inv - o; sq += inv * inv - o * o;                               \
        ring[k] = inv; } }

    // prologue: chunks 0,1 in regs; write 0
    SLOAD(0, rA); SLOAD(1, rB);
    SWRITE(0, rA);
    BARRIER();
    // steady pipeline: load c+2 || write c+1 || barrier || consume c
    SLOAD(2, rA);  SWRITE(1, rB); BARRIER(); CPRIME(0, 16);
    SLOAD(3, rB);  SWRITE(2, rA); BARRIER(); CPRIME(1, 16);
    SLOAD(4, rA);  SWRITE(3, rB); BARRIER(); CPRIME(2, 16);
    SLOAD(5, rB);  SWRITE(4, rA); BARRIER(); CPRIME(3, 16);
    SLOAD(6, rA);  SWRITE(5, rB); BARRIER(); CPRIME(4, 16);
    SLOAD(7, rB);  SWRITE(6, rA); BARRIER(); CPRIME(5, 16);
    SLOAD(8, rA);  SWRITE(7, rB); BARRIER(); CPRIME(6, 4); CMAIN(6, 4, 16);
    SLOAD(9, rB);  SWRITE(8, rA); BARRIER(); CMAIN(7, 0, 16);
    SLOAD(10, rA); SWRITE(9, rB); BARRIER(); CMAIN(8, 0, 16);
    SWRITE(10, rA);               BARRIER(); CMAIN(9, 0, 16);
                                  BARRIER(); CMAIN(10, 0, 4);

#undef SLOAD
#undef SWRITE
#undef BARRIER
#undef CPRIME
#undef CMAIN
}

extern "C" void kernel_launch(void* const* d_in, const int* in_sizes, int n_in,
                              void* d_out, int out_size, void* d_ws, size_t ws_size,
                              hipStream_t stream) {
    (void)in_sizes; (void)n_in; (void)d_ws; (void)ws_size; (void)out_size;
    const float* x = (const float*)d_in[0];
    float* out = (float*)d_out;
    // 4 bpairs * 256 spans = 1024 blocks * 256 threads
    man_kernel<<<dim3(1024), dim3(256), 0, stream>>>(x, out);
}

// Round 16
// 31.191 us; speedup vs baseline: 1.0155x; 1.0155x over previous
//
#include <hip/hip_runtime.h>

constexpr int KWIN = 100;
constexpr int HK   = 50;
constexpr int TSUB = 64;    // frames per thread (16 main batches of 4)
constexpr int MB   = 4;     // incoming loads per batch (A/B pipelined)
constexpr int PB   = 20;    // prime batch -> 5 batches into ring slots

template <bool REFLECT>
__device__ __forceinline__ int tidx(int t) {
    if constexpr (REFLECT) {
        constexpr int T = 16384;
        t = (t < 0) ? -t : t;
        return (t >= T) ? (2 * T - 2 - t) : t;
    }
    return t;   // interior chunk: linear addressing
}

template <bool REFLECT>
__device__ __forceinline__ void run_chunk(
    const float* __restrict__ xb, float* __restrict__ obt, const int t0)
{
    // obt is pre-offset to frame t0. slot s holds frame t0-50+s after prime;
    // after step k's refill, slot k%100 holds frame t0+k+50. Static indices.
    float ring[KWIN];
    float sx = 0.f, sq = 0.f;

#define PLOAD(KB)                                                             \
    {                                                                         \
        _Pragma("unroll")                                                     \
        for (int j = 0; j < PB; ++j)                                          \
            ring[(KB) * PB + j] =                                             \
                xb[(size_t)tidx<REFLECT>(t0 - HK + (KB) * PB + j) * 128];     \
    }
#define PACC(KB)                                                              \
    {                                                                         \
        _Pragma("unroll")                                                     \
        for (int j = 0; j < PB; ++j) {                                        \
            const float u = ring[(KB) * PB + j];                              \
            sx += u;                                                          \
            sq  = fmaf(u, u, sq);                                             \
        }                                                                     \
    }
    PLOAD(0); PLOAD(1);
    PACC(0);  PLOAD(2);
    PACC(1);  PLOAD(3);
    PACC(2);  PLOAD(4);
    PACC(3);
    PACC(4);
#undef PLOAD
#undef PACC

    const float invK   = 1.0f / (float)KWIN;
    const float invKm1 = 1.0f / (float)(KWIN - 1);
    const float fK     = (float)KWIN;

    float inA[MB], inB[MB];

#define LOADB(IN, KB)                                                         \
    {                                                                         \
        _Pragma("unroll")                                                     \
        for (int j = 0; j < MB; ++j)                                          \
            IN[j] = xb[(size_t)tidx<REFLECT>(t0 + (KB) + j + HK) * 128];      \
    }
#define COMPUTEB(IN, KB)                                                      \
    {                                                                         \
        float ov[MB];                                                         \
        _Pragma("unroll")                                                     \
        for (int j = 0; j < MB; ++j) {                                        \
            const int k = (KB) + j;                                           \
            const float c  = ring[(k + HK) % KWIN];   /* frame t0+k    */     \
            const float o  = ring[k % KWIN];          /* frame t0+k-50 */     \
            const float m  = sx * invK;                                       \
            const float va = fmaxf((sq - fK * m * m) * invKm1, 1e-24f);       \
            const float rs = __builtin_amdgcn_rsqf(va);                       \
            ov[j] = (c - m) * rs;                                             \
            sx += IN[j] - o;                                                  \
            sq += IN[j] * IN[j] - o * o;                                      \
            ring[k % KWIN] = IN[j];                                           \
        }                                                                     \
        _Pragma("unroll")                                                     \
        for (int j = 0; j < MB; ++j)                                          \
            obt[(size_t)((KB) + j) * 128] = ov[j];   /* burst of 4 stores */  \
    }

    LOADB(inA, 0 * MB);
    LOADB(inB, 1 * MB);
    COMPUTEB(inA, 0 * MB);  LOADB(inA, 2 * MB);
    COMPUTEB(inB, 1 * MB);  LOADB(inB, 3 * MB);
    COMPUTEB(inA, 2 * MB);  LOADB(inA, 4 * MB);
    COMPUTEB(inB, 3 * MB);  LOADB(inB, 5 * MB);
    COMPUTEB(inA, 4 * MB);  LOADB(inA, 6 * MB);
    COMPUTEB(inB, 5 * MB);  LOADB(inB, 7 * MB);
    COMPUTEB(inA, 6 * MB);  LOADB(inA, 8 * MB);
    COMPUTEB(inB, 7 * MB);  LOADB(inB, 9 * MB);
    COMPUTEB(inA, 8 * MB);  LOADB(inA, 10 * MB);
    COMPUTEB(inB, 9 * MB);  LOADB(inB, 11 * MB);
    COMPUTEB(inA, 10 * MB); LOADB(inA, 12 * MB);
    COMPUTEB(inB, 11 * MB); LOADB(inB, 13 * MB);
    COMPUTEB(inA, 12 * MB); LOADB(inA, 14 * MB);
    COMPUTEB(inB, 13 * MB); LOADB(inB, 15 * MB);
    COMPUTEB(inA, 14 * MB);
    COMPUTEB(inB, 15 * MB);

#undef LOADB
#undef COMPUTEB
}

__global__ __launch_bounds__(256, 2) void man_kernel(
    const float* __restrict__ x, float* __restrict__ out)
{
    constexpr int T = 16384, D = 128;

    const int i   = blockIdx.x;                  // 0..1023
    const int bb  = (i & 7) * 128 + (i >> 3);    // XCD (i&7) owns batch b
    const int b   = bb >> 7;                     // 0..7
    const int seg = bb & 127;                    // pair of adjacent chunks
    const int w   = threadIdx.x >> 7;            // 0..1 chunk within pair
    const int tid = threadIdx.x & 127;           // d column
    const int t0  = (seg * 2 + w) * TSUB;

    const float* __restrict__ xb = x + (size_t)b * T * D + tid;
    float* __restrict__ obt = out + (size_t)b * T * D + (size_t)t0 * D + tid;

    if (t0 >= HK && t0 + TSUB - 1 + HK < T) {
        run_chunk<false>(xb, obt, t0);
    } else {
        run_chunk<true>(xb, obt, t0);
    }
}

extern "C" void kernel_launch(void* const* d_in, const int* in_sizes, int n_in,
                              void* d_out, int out_size, void* d_ws, size_t ws_size,
                              hipStream_t stream) {
    (void)in_sizes; (void)n_in; (void)d_ws; (void)ws_size; (void)out_size;
    const float* x = (const float*)d_in[0];
    float* out = (float*)d_out;
    // 8 b * 256 chunks * 128 d = 262144 threads = 1024 blocks * 256
    man_kernel<<<dim3(1024), dim3(256), 0, stream>>>(x, out);
}